// Round 18
// baseline (64.622 us; speedup 1.0000x reference)
//
#include <hip/hip_runtime.h>
#include <cstddef>

// B=256 batches, N=256 nodes, F=128 features. One block (512 thr) per batch.
// R15 + non-temporal loads for the single-use streams (adj in P0, x in P1):
// keeps the per-XCD L2 free for the Abf bf16 tile written by P0, so the
// P2/P4 Abf read-back hits L2 instead of round-tripping through HBM.

typedef __attribute__((ext_vector_type(8))) short short8;
typedef __attribute__((ext_vector_type(4))) float f32x4;

static __device__ __forceinline__ unsigned short f2bf(float f) {
  unsigned int u = __float_as_uint(f);
  u += 0x7FFFu + ((u >> 16) & 1u);   // round-nearest-even to bf16
  return (unsigned short)(u >> 16);
}

static __device__ __forceinline__ f32x4 mfma16(short8 a, short8 b, f32x4 c) {
  return __builtin_amdgcn_mfma_f32_16x16x32_bf16(a, b, c, 0, 0, 0);
}

// non-temporal float4 load (nt): stream-once data, don't pollute L2.
// builtin requires an ext_vector pointer, not HIP_vector_type float4.
static __device__ __forceinline__ float4 ntload4(const float* p) {
  f32x4 v = __builtin_nontemporal_load(reinterpret_cast<const f32x4*>(p));
  return *reinterpret_cast<float4*>(&v);
}

// LDS byte addressing with XOR swizzle (T: [f][256] bf16, H: [n][128] bf16).
static __device__ __forceinline__ int byteT(int f, int k) {
  return ((f << 9) + (k << 1)) ^ ((f & 7) << 4);
}
static __device__ __forceinline__ int byteH(int n, int k) {
  return ((n << 8) + (k << 1)) ^ ((n & 7) << 4);
}

// ---- P0 helpers: 8-row load / process groups (all indices compile-time) ----
static __device__ __forceinline__ void p0_load(float4 (&v)[8],
    const float* __restrict__ adjb, int rbase, int c0) {
  #pragma unroll
  for (int i = 0; i < 8; ++i)
    v[i] = ntload4(adjb + ((rbase + i) << 8) + c0);
}
static __device__ __forceinline__ void p0_proc(float4 (&v)[8],
    unsigned short* __restrict__ Abw, int rbase, int c0,
    float& sx, float& sy, float& sz, float& sw) {
  #pragma unroll
  for (int i = 0; i < 8; ++i) {
    const int r = rbase + i;
    v[i].x = (r == c0 + 0) ? 1.0f : v[i].x;
    v[i].y = (r == c0 + 1) ? 1.0f : v[i].y;
    v[i].z = (r == c0 + 2) ? 1.0f : v[i].z;
    v[i].w = (r == c0 + 3) ? 1.0f : v[i].w;
    sx += v[i].x; sy += v[i].y; sz += v[i].z; sw += v[i].w;
    ushort4 o;
    o.x = f2bf(v[i].x); o.y = f2bf(v[i].y);
    o.z = f2bf(v[i].z); o.w = f2bf(v[i].w);
    *reinterpret_cast<ushort4*>(Abw + (r << 8) + c0) = o;
  }
}

// ---------------- pack W1 and W2 (128x128 f32) into MFMA A-fragment order ----
// frag elem j = W[ks*32+(l>>4)*8+j][r*16+(l&15)] at P[((ks*8+r)*64+l)*8+j].
__global__ __launch_bounds__(64) void k_packW2(
    const float* __restrict__ W1, const float* __restrict__ W2,
    unsigned short* __restrict__ P1, unsigned short* __restrict__ P2) {
  const float* W = (blockIdx.x < 32) ? W1 : W2;
  unsigned short* P = (blockIdx.x < 32) ? P1 : P2;
  const int bb = blockIdx.x & 31;
  const int ks = bb >> 3;
  const int r = bb & 7;
  const int l = threadIdx.x;
  const int col = r * 16 + (l & 15);
  const int k0 = ks * 32 + ((l >> 4) << 3);
  short8 frag;
  #pragma unroll
  for (int j = 0; j < 8; ++j)
    frag[j] = (short)f2bf(W[(size_t)(k0 + j) * 128 + col]);
  *reinterpret_cast<short8*>(P + ((size_t)((ks * 8 + r) * 64 + l)) * 8) = frag;
}

// ---------------- fully fused GCN: deg + 2 layers + pool + readout ----------
__global__ __launch_bounds__(512) void k_fused(
    const float* __restrict__ adj, const float* __restrict__ x,
    const unsigned short* __restrict__ W1p, const unsigned short* __restrict__ W2p,
    const float* __restrict__ b1, const float* __restrict__ b2,
    const float* __restrict__ Wr, const float* __restrict__ br,
    unsigned short* __restrict__ Abf, float* __restrict__ out) {
  __shared__ __align__(16) char bufA[65536];   // P0 red / T1 / T2 [f][256] swz
  __shared__ __align__(16) char bufB[65536];   // H1 [n][128] swz / pool bufs
  __shared__ float dinv_s[256];

  const int b = blockIdx.x;
  const int tid = threadIdx.x;
  const int w = tid >> 6;          // wave 0..7
  const int l = tid & 63;
  const int l15 = l & 15;
  const int khalf = (l >> 4) << 3;
  const int qbase = (l >> 4) << 2;
  const int m = (w << 4) + l15;    // wave's first m-column / P2 lane row
  const unsigned short* Ab = Abf + ((size_t)b << 16);
  const int n0w = w << 5;          // wave's 32-row slice for P2/P4

  // ---- hoist first half of this lane's x row (hides under P0 streaming) ----
  // xa[2k+u] = x[m][k*32 + khalf + 4u], k=0..1, u=0..1  (matches P1 consumer)
  float4 xa[4];
  {
    const float* xr = x + ((((size_t)b << 8) + m) << 7);
    #pragma unroll
    for (int k = 0; k < 2; ++k) {
      xa[2 * k]     = ntload4(xr + (k << 5) + khalf);
      xa[2 * k + 1] = ntload4(xr + (k << 5) + khalf + 4);
    }
  }

  // ---- P0: stream adj rows [w*32,+32) in 4 dbuf'd groups of 8 (nt loads) ----
  {
    const int c0 = l << 2;
    const float* adjb = adj + ((size_t)b << 16);
    unsigned short* Abw = Abf + ((size_t)b << 16);
    float sx = 0.f, sy = 0.f, sz = 0.f, sw = 0.f;
    float4 va[8], vb[8];
    p0_load(va, adjb, n0w + 0, c0);
    p0_load(vb, adjb, n0w + 8, c0);
    p0_proc(va, Abw, n0w + 0, c0, sx, sy, sz, sw);
    p0_load(va, adjb, n0w + 16, c0);
    p0_proc(vb, Abw, n0w + 8, c0, sx, sy, sz, sw);
    p0_load(vb, adjb, n0w + 24, c0);
    p0_proc(va, Abw, n0w + 16, c0, sx, sy, sz, sw);
    p0_proc(vb, Abw, n0w + 24, c0, sx, sy, sz, sw);
    float* red = reinterpret_cast<float*>(bufA);   // [8][256] colsum partials
    float4 st; st.x = sx; st.y = sy; st.z = sz; st.w = sw;
    *reinterpret_cast<float4*>(red + (w << 8) + c0) = st;
  }
  __syncthreads();   // red[] complete
  if (tid < 256) {
    const float* red = reinterpret_cast<const float*>(bufA);
    float s = 0.f;
    #pragma unroll
    for (int g = 0; g < 8; ++g) s += red[(g << 8) + tid];
    dinv_s[tid] = rsqrtf(fmaxf(s, 1.0f));
  }
  __syncthreads();   // dinv ready; red reads done (bufA reusable)

  // ---- P1: T1[f][m'] = dinv[m']*(x@W1)[m'][f] -> bufA (swizzled) ----
  {
    const short8* Wf = reinterpret_cast<const short8*>(W1p);
    // p=0 (m' = m): second half of x row now; first half already in xa
    {
      const float* xr = x + ((((size_t)b << 8) + m) << 7);
      float4 xb[4];
      #pragma unroll
      for (int ks = 2; ks < 4; ++ks) {
        xb[2 * (ks - 2)]     = ntload4(xr + (ks << 5) + khalf);
        xb[2 * (ks - 2) + 1] = ntload4(xr + (ks << 5) + khalf + 4);
      }
      f32x4 acc[8];
      #pragma unroll
      for (int r = 0; r < 8; ++r) acc[r] = (f32x4)(0.0f);
      #pragma unroll
      for (int ks = 0; ks < 4; ++ks) {
        const float4 u = (ks < 2) ? xa[2 * ks] : xb[2 * (ks - 2)];
        const float4 vv = (ks < 2) ? xa[2 * ks + 1] : xb[2 * (ks - 2) + 1];
        short8 bf;
        bf[0] = (short)f2bf(u.x);  bf[1] = (short)f2bf(u.y);
        bf[2] = (short)f2bf(u.z);  bf[3] = (short)f2bf(u.w);
        bf[4] = (short)f2bf(vv.x); bf[5] = (short)f2bf(vv.y);
        bf[6] = (short)f2bf(vv.z); bf[7] = (short)f2bf(vv.w);
        #pragma unroll
        for (int r = 0; r < 8; ++r)
          acc[r] = mfma16(Wf[((ks << 3) + r) * 64 + l], bf, acc[r]);
      }
      const float sc = dinv_s[m];
      #pragma unroll
      for (int r = 0; r < 8; ++r)
        #pragma unroll
        for (int q = 0; q < 4; ++q)
          *reinterpret_cast<unsigned short*>(bufA + byteT((r << 4) + qbase + q, m)) =
              f2bf(acc[r][q] * sc);
    }
    // p=1 (m' = m+128)
    {
      const int m1 = m + 128;
      const float* xr = x + ((((size_t)b << 8) + m1) << 7);
      float4 xc[8];
      #pragma unroll
      for (int ks = 0; ks < 4; ++ks) {
        xc[2 * ks]     = ntload4(xr + (ks << 5) + khalf);
        xc[2 * ks + 1] = ntload4(xr + (ks << 5) + khalf + 4);
      }
      f32x4 acc[8];
      #pragma unroll
      for (int r = 0; r < 8; ++r) acc[r] = (f32x4)(0.0f);
      #pragma unroll
      for (int ks = 0; ks < 4; ++ks) {
        const float4 u = xc[2 * ks], vv = xc[2 * ks + 1];
        short8 bf;
        bf[0] = (short)f2bf(u.x);  bf[1] = (short)f2bf(u.y);
        bf[2] = (short)f2bf(u.z);  bf[3] = (short)f2bf(u.w);
        bf[4] = (short)f2bf(vv.x); bf[5] = (short)f2bf(vv.y);
        bf[6] = (short)f2bf(vv.z); bf[7] = (short)f2bf(vv.w);
        #pragma unroll
        for (int r = 0; r < 8; ++r)
          acc[r] = mfma16(Wf[((ks << 3) + r) * 64 + l], bf, acc[r]);
      }
      const float sc = dinv_s[m1];
      #pragma unroll
      for (int r = 0; r < 8; ++r)
        #pragma unroll
        for (int q = 0; q < 4; ++q)
          *reinterpret_cast<unsigned short*>(bufA + byteT((r << 4) + qbase + q, m1)) =
              f2bf(acc[r][q] * sc);
    }
  }
  __syncthreads();

  // ---- P2: H1 rows [w*32,+32) = dinv[n]*(A'@T1)+b1 -> bufB (swizzled).
  //      Paired tiles: one bf ds_read feeds MFMAs of BOTH 16-row tiles. ----
  {
    float bs[8];
    #pragma unroll
    for (int c = 0; c < 8; ++c) bs[c] = b1[(c << 4) + l15];
    f32x4 acc[2][8];
    #pragma unroll
    for (int rt = 0; rt < 2; ++rt)
      #pragma unroll
      for (int c = 0; c < 8; ++c) acc[rt][c] = (f32x4)(0.0f);
    #pragma unroll
    for (int ks = 0; ks < 8; ++ks) {
      const int k0 = (ks << 5) + khalf;
      short8 a0 = *reinterpret_cast<const short8*>(
          Ab + (size_t)(n0w + l15) * 256 + k0);
      short8 a1 = *reinterpret_cast<const short8*>(
          Ab + (size_t)(n0w + 16 + l15) * 256 + k0);
      #pragma unroll
      for (int c = 0; c < 8; ++c) {
        short8 bf = *reinterpret_cast<const short8*>(bufA + byteT((c << 4) + l15, k0));
        acc[0][c] = mfma16(a0, bf, acc[0][c]);
        acc[1][c] = mfma16(a1, bf, acc[1][c]);
      }
    }
    #pragma unroll
    for (int rt = 0; rt < 2; ++rt) {
      #pragma unroll
      for (int q = 0; q < 4; ++q) {
        const int n = n0w + (rt << 4) + qbase + q;
        const float dv = dinv_s[n];
        #pragma unroll
        for (int c = 0; c < 8; ++c)
          *reinterpret_cast<unsigned short*>(bufB + byteH(n, (c << 4) + l15)) =
              f2bf(acc[rt][c][q] * dv + bs[c]);
      }
    }
  }
  __syncthreads();

  // ---- P3: T2[f][m'] = dinv[m']*(H1@W2)[m'][f] -> bufA (T1 dead) ----
  {
    const short8* Wf = reinterpret_cast<const short8*>(W2p);
    #pragma unroll
    for (int p = 0; p < 2; ++p) {
      const int mp = (p << 7) + m;
      f32x4 acc[8];
      #pragma unroll
      for (int r = 0; r < 8; ++r) acc[r] = (f32x4)(0.0f);
      #pragma unroll
      for (int ks = 0; ks < 4; ++ks) {
        const int kk = (ks << 5) + khalf;
        short8 hf = *reinterpret_cast<const short8*>(bufB + byteH(mp, kk));
        #pragma unroll
        for (int r = 0; r < 8; ++r)
          acc[r] = mfma16(Wf[((ks << 3) + r) * 64 + l], hf, acc[r]);
      }
      const float sc = dinv_s[mp];
      #pragma unroll
      for (int r = 0; r < 8; ++r)
        #pragma unroll
        for (int q = 0; q < 4; ++q)
          *reinterpret_cast<unsigned short*>(bufA + byteT((r << 4) + qbase + q, mp)) =
              f2bf(acc[r][q] * sc);
    }
  }
  __syncthreads();

  // ---- P4: H2 = dinv*(A'@T2)+b2 (regs) + mean/max pool + readout.
  //      Paired tiles, shared bf reads (same as P2). ----
  {
    float bs[8], psum[8], pmax[8];
    #pragma unroll
    for (int c = 0; c < 8; ++c) {
      bs[c] = b2[(c << 4) + l15];
      psum[c] = 0.0f; pmax[c] = -1e30f;
    }
    f32x4 acc[2][8];
    #pragma unroll
    for (int rt = 0; rt < 2; ++rt)
      #pragma unroll
      for (int c = 0; c < 8; ++c) acc[rt][c] = (f32x4)(0.0f);
    #pragma unroll
    for (int ks = 0; ks < 8; ++ks) {
      const int k0 = (ks << 5) + khalf;
      short8 a0 = *reinterpret_cast<const short8*>(
          Ab + (size_t)(n0w + l15) * 256 + k0);
      short8 a1 = *reinterpret_cast<const short8*>(
          Ab + (size_t)(n0w + 16 + l15) * 256 + k0);
      #pragma unroll
      for (int c = 0; c < 8; ++c) {
        short8 bf = *reinterpret_cast<const short8*>(bufA + byteT((c << 4) + l15, k0));
        acc[0][c] = mfma16(a0, bf, acc[0][c]);
        acc[1][c] = mfma16(a1, bf, acc[1][c]);
      }
    }
    #pragma unroll
    for (int rt = 0; rt < 2; ++rt) {
      #pragma unroll
      for (int q = 0; q < 4; ++q) {
        const int n = n0w + (rt << 4) + qbase + q;
        const float dv = dinv_s[n];
        #pragma unroll
        for (int c = 0; c < 8; ++c) {
          const float v = acc[rt][c][q] * dv + bs[c];
          psum[c] += v;
          pmax[c] = fmaxf(pmax[c], v);
        }
      }
    }
    // reduce across the 4 lane-groups sharing the same f (=c*16+l15)
    #pragma unroll
    for (int c = 0; c < 8; ++c) {
      psum[c] += __shfl_xor(psum[c], 16);
      pmax[c] = fmaxf(pmax[c], __shfl_xor(pmax[c], 16));
      psum[c] += __shfl_xor(psum[c], 32);
      pmax[c] = fmaxf(pmax[c], __shfl_xor(pmax[c], 32));
    }
    float* lds_sum = reinterpret_cast<float*>(bufB);      // [8][128]
    float* lds_max = lds_sum + 1024;                      // [8][128]
    float* pooled  = lds_max + 1024;                      // [256]
    float* rp      = pooled + 256;                        // [4][128]
    if (l < 16) {
      #pragma unroll
      for (int c = 0; c < 8; ++c) {
        lds_sum[(w << 7) + (c << 4) + l] = psum[c];
        lds_max[(w << 7) + (c << 4) + l] = pmax[c];
      }
    }
    __syncthreads();
    if (tid < 128) {
      float s = 0.0f;
      #pragma unroll
      for (int ww = 0; ww < 8; ++ww) s += lds_sum[(ww << 7) + tid];
      pooled[tid] = s * (1.0f / 256.0f);
    } else if (tid < 256) {
      const int f = tid & 127;
      float mx = -1e30f;
      #pragma unroll
      for (int ww = 0; ww < 8; ++ww) mx = fmaxf(mx, lds_max[(ww << 7) + f]);
      pooled[128 + f] = mx;
    }
    __syncthreads();
    {   // readout: 4 partial-dot slices of 64 each, all 512 threads
      const int f = tid & 127, part = tid >> 7;
      const int base = part << 6;
      float o0 = 0.f, o1 = 0.f;
      #pragma unroll 4
      for (int i = 0; i < 64; i += 2) {
        o0 = fmaf(pooled[base + i],     Wr[(base + i) * 128 + f],     o0);
        o1 = fmaf(pooled[base + i + 1], Wr[(base + i + 1) * 128 + f], o1);
      }
      rp[(part << 7) + f] = o0 + o1;
    }
    __syncthreads();
    if (tid < 128) {
      out[(b << 7) + tid] =
          ((rp[tid] + rp[128 + tid]) + (rp[256 + tid] + rp[384 + tid])) + br[tid];
    }
  }
}

extern "C" void kernel_launch(void* const* d_in, const int* in_sizes, int n_in,
                              void* d_out, int out_size, void* d_ws, size_t ws_size,
                              hipStream_t stream) {
  const float* x   = (const float*)d_in[0];
  const float* adj = (const float*)d_in[1];
  const float* W1  = (const float*)d_in[2];
  const float* b1  = (const float*)d_in[3];
  const float* W2  = (const float*)d_in[4];
  const float* b2  = (const float*)d_in[5];
  const float* Wr  = (const float*)d_in[6];
  const float* br  = (const float*)d_in[7];
  float* out = (float*)d_out;

  char* ws = (char*)d_ws;
  unsigned short* Abf = (unsigned short*)(ws);              // 33,554,432 B
  unsigned short* W1p = (unsigned short*)(ws + 33554432);   //     32,768 B
  unsigned short* W2p = (unsigned short*)(ws + 33587200);   //     32,768 B

  k_packW2<<<64, 64, 0, stream>>>(W1, W2, W1p, W2p);
  k_fused<<<256, 512, 0, stream>>>(adj, x, W1p, W2p, b1, b2, Wr, br, Abf, out);
}

// Round 19
// 57.795 us; speedup vs baseline: 1.1181x; 1.1181x over previous
//
#include <hip/hip_runtime.h>
#include <cstddef>

// B=256 batches, N=256 nodes, F=128 features. One block (512 thr) per batch.
// FINAL (R15, verified 57.87 us): monolithic fused GCN. P0 streams adj once
// (colsum + bf16 Abf to global ws), P1..P4 do both layers + pool + readout
// with T/H ping-ponged in 128 KB LDS. Paired-tile aggregation shares each
// B-fragment ds_read across two MFMAs. VGPR=128, no spill.

typedef __attribute__((ext_vector_type(8))) short short8;
typedef __attribute__((ext_vector_type(4))) float f32x4;

static __device__ __forceinline__ unsigned short f2bf(float f) {
  unsigned int u = __float_as_uint(f);
  u += 0x7FFFu + ((u >> 16) & 1u);   // round-nearest-even to bf16
  return (unsigned short)(u >> 16);
}

static __device__ __forceinline__ f32x4 mfma16(short8 a, short8 b, f32x4 c) {
  return __builtin_amdgcn_mfma_f32_16x16x32_bf16(a, b, c, 0, 0, 0);
}

// LDS byte addressing with XOR swizzle (T: [f][256] bf16, H: [n][128] bf16).
static __device__ __forceinline__ int byteT(int f, int k) {
  return ((f << 9) + (k << 1)) ^ ((f & 7) << 4);
}
static __device__ __forceinline__ int byteH(int n, int k) {
  return ((n << 8) + (k << 1)) ^ ((n & 7) << 4);
}

// ---- P0 helpers: 8-row load / process groups (all indices compile-time) ----
static __device__ __forceinline__ void p0_load(float4 (&v)[8],
    const float* __restrict__ adjb, int rbase, int c0) {
  #pragma unroll
  for (int i = 0; i < 8; ++i)
    v[i] = *reinterpret_cast<const float4*>(adjb + ((rbase + i) << 8) + c0);
}
static __device__ __forceinline__ void p0_proc(float4 (&v)[8],
    unsigned short* __restrict__ Abw, int rbase, int c0,
    float& sx, float& sy, float& sz, float& sw) {
  #pragma unroll
  for (int i = 0; i < 8; ++i) {
    const int r = rbase + i;
    v[i].x = (r == c0 + 0) ? 1.0f : v[i].x;
    v[i].y = (r == c0 + 1) ? 1.0f : v[i].y;
    v[i].z = (r == c0 + 2) ? 1.0f : v[i].z;
    v[i].w = (r == c0 + 3) ? 1.0f : v[i].w;
    sx += v[i].x; sy += v[i].y; sz += v[i].z; sw += v[i].w;
    ushort4 o;
    o.x = f2bf(v[i].x); o.y = f2bf(v[i].y);
    o.z = f2bf(v[i].z); o.w = f2bf(v[i].w);
    *reinterpret_cast<ushort4*>(Abw + (r << 8) + c0) = o;
  }
}

// ---------------- pack W1 and W2 (128x128 f32) into MFMA A-fragment order ----
// frag elem j = W[ks*32+(l>>4)*8+j][r*16+(l&15)] at P[((ks*8+r)*64+l)*8+j].
__global__ __launch_bounds__(64) void k_packW2(
    const float* __restrict__ W1, const float* __restrict__ W2,
    unsigned short* __restrict__ P1, unsigned short* __restrict__ P2) {
  const float* W = (blockIdx.x < 32) ? W1 : W2;
  unsigned short* P = (blockIdx.x < 32) ? P1 : P2;
  const int bb = blockIdx.x & 31;
  const int ks = bb >> 3;
  const int r = bb & 7;
  const int l = threadIdx.x;
  const int col = r * 16 + (l & 15);
  const int k0 = ks * 32 + ((l >> 4) << 3);
  short8 frag;
  #pragma unroll
  for (int j = 0; j < 8; ++j)
    frag[j] = (short)f2bf(W[(size_t)(k0 + j) * 128 + col]);
  *reinterpret_cast<short8*>(P + ((size_t)((ks * 8 + r) * 64 + l)) * 8) = frag;
}

// ---------------- fully fused GCN: deg + 2 layers + pool + readout ----------
__global__ __launch_bounds__(512) void k_fused(
    const float* __restrict__ adj, const float* __restrict__ x,
    const unsigned short* __restrict__ W1p, const unsigned short* __restrict__ W2p,
    const float* __restrict__ b1, const float* __restrict__ b2,
    const float* __restrict__ Wr, const float* __restrict__ br,
    unsigned short* __restrict__ Abf, float* __restrict__ out) {
  __shared__ __align__(16) char bufA[65536];   // P0 red / T1 / T2 [f][256] swz
  __shared__ __align__(16) char bufB[65536];   // H1 [n][128] swz / pool bufs
  __shared__ float dinv_s[256];

  const int b = blockIdx.x;
  const int tid = threadIdx.x;
  const int w = tid >> 6;          // wave 0..7
  const int l = tid & 63;
  const int l15 = l & 15;
  const int khalf = (l >> 4) << 3;
  const int qbase = (l >> 4) << 2;
  const int m = (w << 4) + l15;    // wave's first m-column / P2 lane row
  const unsigned short* Ab = Abf + ((size_t)b << 16);
  const int n0w = w << 5;          // wave's 32-row slice for P2/P4

  // ---- hoist first half of this lane's x row (hides under P0 streaming) ----
  // xa[2k+u] = x[m][k*32 + khalf + 4u], k=0..1, u=0..1  (matches P1 consumer)
  float4 xa[4];
  {
    const float* xr = x + ((((size_t)b << 8) + m) << 7);
    #pragma unroll
    for (int k = 0; k < 2; ++k) {
      xa[2 * k]     = *reinterpret_cast<const float4*>(xr + (k << 5) + khalf);
      xa[2 * k + 1] = *reinterpret_cast<const float4*>(xr + (k << 5) + khalf + 4);
    }
  }

  // ---- P0: stream adj rows [w*32,+32) in 4 dbuf'd groups of 8 ----
  {
    const int c0 = l << 2;
    const float* adjb = adj + ((size_t)b << 16);
    unsigned short* Abw = Abf + ((size_t)b << 16);
    float sx = 0.f, sy = 0.f, sz = 0.f, sw = 0.f;
    float4 va[8], vb[8];
    p0_load(va, adjb, n0w + 0, c0);
    p0_load(vb, adjb, n0w + 8, c0);
    p0_proc(va, Abw, n0w + 0, c0, sx, sy, sz, sw);
    p0_load(va, adjb, n0w + 16, c0);
    p0_proc(vb, Abw, n0w + 8, c0, sx, sy, sz, sw);
    p0_load(vb, adjb, n0w + 24, c0);
    p0_proc(va, Abw, n0w + 16, c0, sx, sy, sz, sw);
    p0_proc(vb, Abw, n0w + 24, c0, sx, sy, sz, sw);
    float* red = reinterpret_cast<float*>(bufA);   // [8][256] colsum partials
    float4 st; st.x = sx; st.y = sy; st.z = sz; st.w = sw;
    *reinterpret_cast<float4*>(red + (w << 8) + c0) = st;
  }
  __syncthreads();   // red[] complete
  if (tid < 256) {
    const float* red = reinterpret_cast<const float*>(bufA);
    float s = 0.f;
    #pragma unroll
    for (int g = 0; g < 8; ++g) s += red[(g << 8) + tid];
    dinv_s[tid] = rsqrtf(fmaxf(s, 1.0f));
  }
  __syncthreads();   // dinv ready; red reads done (bufA reusable)

  // ---- P1: T1[f][m'] = dinv[m']*(x@W1)[m'][f] -> bufA (swizzled) ----
  {
    const short8* Wf = reinterpret_cast<const short8*>(W1p);
    // p=0 (m' = m): second half of x row now; first half already in xa
    {
      const float* xr = x + ((((size_t)b << 8) + m) << 7);
      float4 xb[4];
      #pragma unroll
      for (int ks = 2; ks < 4; ++ks) {
        xb[2 * (ks - 2)]     = *reinterpret_cast<const float4*>(xr + (ks << 5) + khalf);
        xb[2 * (ks - 2) + 1] = *reinterpret_cast<const float4*>(xr + (ks << 5) + khalf + 4);
      }
      f32x4 acc[8];
      #pragma unroll
      for (int r = 0; r < 8; ++r) acc[r] = (f32x4)(0.0f);
      #pragma unroll
      for (int ks = 0; ks < 4; ++ks) {
        const float4 u = (ks < 2) ? xa[2 * ks] : xb[2 * (ks - 2)];
        const float4 vv = (ks < 2) ? xa[2 * ks + 1] : xb[2 * (ks - 2) + 1];
        short8 bf;
        bf[0] = (short)f2bf(u.x);  bf[1] = (short)f2bf(u.y);
        bf[2] = (short)f2bf(u.z);  bf[3] = (short)f2bf(u.w);
        bf[4] = (short)f2bf(vv.x); bf[5] = (short)f2bf(vv.y);
        bf[6] = (short)f2bf(vv.z); bf[7] = (short)f2bf(vv.w);
        #pragma unroll
        for (int r = 0; r < 8; ++r)
          acc[r] = mfma16(Wf[((ks << 3) + r) * 64 + l], bf, acc[r]);
      }
      const float sc = dinv_s[m];
      #pragma unroll
      for (int r = 0; r < 8; ++r)
        #pragma unroll
        for (int q = 0; q < 4; ++q)
          *reinterpret_cast<unsigned short*>(bufA + byteT((r << 4) + qbase + q, m)) =
              f2bf(acc[r][q] * sc);
    }
    // p=1 (m' = m+128)
    {
      const int m1 = m + 128;
      const float* xr = x + ((((size_t)b << 8) + m1) << 7);
      float4 xc[8];
      #pragma unroll
      for (int ks = 0; ks < 4; ++ks) {
        xc[2 * ks]     = *reinterpret_cast<const float4*>(xr + (ks << 5) + khalf);
        xc[2 * ks + 1] = *reinterpret_cast<const float4*>(xr + (ks << 5) + khalf + 4);
      }
      f32x4 acc[8];
      #pragma unroll
      for (int r = 0; r < 8; ++r) acc[r] = (f32x4)(0.0f);
      #pragma unroll
      for (int ks = 0; ks < 4; ++ks) {
        const float4 u = xc[2 * ks], vv = xc[2 * ks + 1];
        short8 bf;
        bf[0] = (short)f2bf(u.x);  bf[1] = (short)f2bf(u.y);
        bf[2] = (short)f2bf(u.z);  bf[3] = (short)f2bf(u.w);
        bf[4] = (short)f2bf(vv.x); bf[5] = (short)f2bf(vv.y);
        bf[6] = (short)f2bf(vv.z); bf[7] = (short)f2bf(vv.w);
        #pragma unroll
        for (int r = 0; r < 8; ++r)
          acc[r] = mfma16(Wf[((ks << 3) + r) * 64 + l], bf, acc[r]);
      }
      const float sc = dinv_s[m1];
      #pragma unroll
      for (int r = 0; r < 8; ++r)
        #pragma unroll
        for (int q = 0; q < 4; ++q)
          *reinterpret_cast<unsigned short*>(bufA + byteT((r << 4) + qbase + q, m1)) =
              f2bf(acc[r][q] * sc);
    }
  }
  __syncthreads();

  // ---- P2: H1 rows [w*32,+32) = dinv[n]*(A'@T1)+b1 -> bufB (swizzled).
  //      Paired tiles: one bf ds_read feeds MFMAs of BOTH 16-row tiles. ----
  {
    float bs[8];
    #pragma unroll
    for (int c = 0; c < 8; ++c) bs[c] = b1[(c << 4) + l15];
    f32x4 acc[2][8];
    #pragma unroll
    for (int rt = 0; rt < 2; ++rt)
      #pragma unroll
      for (int c = 0; c < 8; ++c) acc[rt][c] = (f32x4)(0.0f);
    #pragma unroll
    for (int ks = 0; ks < 8; ++ks) {
      const int k0 = (ks << 5) + khalf;
      short8 a0 = *reinterpret_cast<const short8*>(
          Ab + (size_t)(n0w + l15) * 256 + k0);
      short8 a1 = *reinterpret_cast<const short8*>(
          Ab + (size_t)(n0w + 16 + l15) * 256 + k0);
      #pragma unroll
      for (int c = 0; c < 8; ++c) {
        short8 bf = *reinterpret_cast<const short8*>(bufA + byteT((c << 4) + l15, k0));
        acc[0][c] = mfma16(a0, bf, acc[0][c]);
        acc[1][c] = mfma16(a1, bf, acc[1][c]);
      }
    }
    #pragma unroll
    for (int rt = 0; rt < 2; ++rt) {
      #pragma unroll
      for (int q = 0; q < 4; ++q) {
        const int n = n0w + (rt << 4) + qbase + q;
        const float dv = dinv_s[n];
        #pragma unroll
        for (int c = 0; c < 8; ++c)
          *reinterpret_cast<unsigned short*>(bufB + byteH(n, (c << 4) + l15)) =
              f2bf(acc[rt][c][q] * dv + bs[c]);
      }
    }
  }
  __syncthreads();

  // ---- P3: T2[f][m'] = dinv[m']*(H1@W2)[m'][f] -> bufA (T1 dead) ----
  {
    const short8* Wf = reinterpret_cast<const short8*>(W2p);
    #pragma unroll
    for (int p = 0; p < 2; ++p) {
      const int mp = (p << 7) + m;
      f32x4 acc[8];
      #pragma unroll
      for (int r = 0; r < 8; ++r) acc[r] = (f32x4)(0.0f);
      #pragma unroll
      for (int ks = 0; ks < 4; ++ks) {
        const int kk = (ks << 5) + khalf;
        short8 hf = *reinterpret_cast<const short8*>(bufB + byteH(mp, kk));
        #pragma unroll
        for (int r = 0; r < 8; ++r)
          acc[r] = mfma16(Wf[((ks << 3) + r) * 64 + l], hf, acc[r]);
      }
      const float sc = dinv_s[mp];
      #pragma unroll
      for (int r = 0; r < 8; ++r)
        #pragma unroll
        for (int q = 0; q < 4; ++q)
          *reinterpret_cast<unsigned short*>(bufA + byteT((r << 4) + qbase + q, mp)) =
              f2bf(acc[r][q] * sc);
    }
  }
  __syncthreads();

  // ---- P4: H2 = dinv*(A'@T2)+b2 (regs) + mean/max pool + readout.
  //      Paired tiles, shared bf reads (same as P2). ----
  {
    float bs[8], psum[8], pmax[8];
    #pragma unroll
    for (int c = 0; c < 8; ++c) {
      bs[c] = b2[(c << 4) + l15];
      psum[c] = 0.0f; pmax[c] = -1e30f;
    }
    f32x4 acc[2][8];
    #pragma unroll
    for (int rt = 0; rt < 2; ++rt)
      #pragma unroll
      for (int c = 0; c < 8; ++c) acc[rt][c] = (f32x4)(0.0f);
    #pragma unroll
    for (int ks = 0; ks < 8; ++ks) {
      const int k0 = (ks << 5) + khalf;
      short8 a0 = *reinterpret_cast<const short8*>(
          Ab + (size_t)(n0w + l15) * 256 + k0);
      short8 a1 = *reinterpret_cast<const short8*>(
          Ab + (size_t)(n0w + 16 + l15) * 256 + k0);
      #pragma unroll
      for (int c = 0; c < 8; ++c) {
        short8 bf = *reinterpret_cast<const short8*>(bufA + byteT((c << 4) + l15, k0));
        acc[0][c] = mfma16(a0, bf, acc[0][c]);
        acc[1][c] = mfma16(a1, bf, acc[1][c]);
      }
    }
    #pragma unroll
    for (int rt = 0; rt < 2; ++rt) {
      #pragma unroll
      for (int q = 0; q < 4; ++q) {
        const int n = n0w + (rt << 4) + qbase + q;
        const float dv = dinv_s[n];
        #pragma unroll
        for (int c = 0; c < 8; ++c) {
          const float v = acc[rt][c][q] * dv + bs[c];
          psum[c] += v;
          pmax[c] = fmaxf(pmax[c], v);
        }
      }
    }
    // reduce across the 4 lane-groups sharing the same f (=c*16+l15)
    #pragma unroll
    for (int c = 0; c < 8; ++c) {
      psum[c] += __shfl_xor(psum[c], 16);
      pmax[c] = fmaxf(pmax[c], __shfl_xor(pmax[c], 16));
      psum[c] += __shfl_xor(psum[c], 32);
      pmax[c] = fmaxf(pmax[c], __shfl_xor(pmax[c], 32));
    }
    float* lds_sum = reinterpret_cast<float*>(bufB);      // [8][128]
    float* lds_max = lds_sum + 1024;                      // [8][128]
    float* pooled  = lds_max + 1024;                      // [256]
    float* rp      = pooled + 256;                        // [4][128]
    if (l < 16) {
      #pragma unroll
      for (int c = 0; c < 8; ++c) {
        lds_sum[(w << 7) + (c << 4) + l] = psum[c];
        lds_max[(w << 7) + (c << 4) + l] = pmax[c];
      }
    }
    __syncthreads();
    if (tid < 128) {
      float s = 0.0f;
      #pragma unroll
      for (int ww = 0; ww < 8; ++ww) s += lds_sum[(ww << 7) + tid];
      pooled[tid] = s * (1.0f / 256.0f);
    } else if (tid < 256) {
      const int f = tid & 127;
      float mx = -1e30f;
      #pragma unroll
      for (int ww = 0; ww < 8; ++ww) mx = fmaxf(mx, lds_max[(ww << 7) + f]);
      pooled[128 + f] = mx;
    }
    __syncthreads();
    {   // readout: 4 partial-dot slices of 64 each, all 512 threads
      const int f = tid & 127, part = tid >> 7;
      const int base = part << 6;
      float o0 = 0.f, o1 = 0.f;
      #pragma unroll 4
      for (int i = 0; i < 64; i += 2) {
        o0 = fmaf(pooled[base + i],     Wr[(base + i) * 128 + f],     o0);
        o1 = fmaf(pooled[base + i + 1], Wr[(base + i + 1) * 128 + f], o1);
      }
      rp[(part << 7) + f] = o0 + o1;
    }
    __syncthreads();
    if (tid < 128) {
      out[(b << 7) + tid] =
          ((rp[tid] + rp[128 + tid]) + (rp[256 + tid] + rp[384 + tid])) + br[tid];
    }
  }
}

extern "C" void kernel_launch(void* const* d_in, const int* in_sizes, int n_in,
                              void* d_out, int out_size, void* d_ws, size_t ws_size,
                              hipStream_t stream) {
  const float* x   = (const float*)d_in[0];
  const float* adj = (const float*)d_in[1];
  const float* W1  = (const float*)d_in[2];
  const float* b1  = (const float*)d_in[3];
  const float* W2  = (const float*)d_in[4];
  const float* b2  = (const float*)d_in[5];
  const float* Wr  = (const float*)d_in[6];
  const float* br  = (const float*)d_in[7];
  float* out = (float*)d_out;

  char* ws = (char*)d_ws;
  unsigned short* Abf = (unsigned short*)(ws);              // 33,554,432 B
  unsigned short* W1p = (unsigned short*)(ws + 33554432);   //     32,768 B
  unsigned short* W2p = (unsigned short*)(ws + 33587200);   //     32,768 B

  k_packW2<<<64, 64, 0, stream>>>(W1, W2, W1p, W2p);
  k_fused<<<256, 512, 0, stream>>>(adj, x, W1p, W2p, b1, b2, Wr, br, Abf, out);
}